// Round 1
// baseline (295.151 us; speedup 1.0000x reference)
//
#include <hip/hip_runtime.h>
#include <stdint.h>

// Problem dims (QuantizedLinear: out = x @ dequant(q,s)^T + bias)
#define M_DIM 2048
#define K_DIM 4096
#define N_DIM 11008
#define KB2   (K_DIM / 2)     // int32 per W row (one packed byte each)
#define NGRP  (K_DIM / 128)   // 32 scale groups per row

#define BM 128
#define BN 128
#define BK 64

typedef __attribute__((ext_vector_type(8))) short bf16x8;
typedef __attribute__((ext_vector_type(4))) float f32x4;

// f32 -> bf16 RNE (inputs finite; no NaN handling needed)
__device__ __forceinline__ unsigned short f2bf(float f) {
  union { float f; unsigned u; } v; v.f = f;
  return (unsigned short)((v.u + 0x7FFFu + ((v.u >> 16) & 1u)) >> 16);
}

// async global->LDS, 16B per lane; LDS dest must be wave-uniform base (HW adds lane*16)
__device__ __forceinline__ void gload_lds16(const void* g, void* l) {
  __builtin_amdgcn_global_load_lds(
      (__attribute__((address_space(1))) void*)(g),
      (__attribute__((address_space(3))) void*)(l), 16, 0, 0);
}

// ---------------- prepass: x f32 -> bf16 ----------------
__global__ void convert_x_kernel(const float* __restrict__ x,
                                 unsigned short* __restrict__ xb) {
  const size_t total = (size_t)M_DIM * K_DIM / 8;
  for (size_t u = (size_t)blockIdx.x * blockDim.x + threadIdx.x; u < total;
       u += (size_t)gridDim.x * blockDim.x) {
    const float4* src = (const float4*)(x + u * 8);
    float4 f0 = src[0];
    float4 f1 = src[1];
    union { unsigned short h[8]; int4 v; } o;
    o.h[0] = f2bf(f0.x); o.h[1] = f2bf(f0.y); o.h[2] = f2bf(f0.z); o.h[3] = f2bf(f0.w);
    o.h[4] = f2bf(f1.x); o.h[5] = f2bf(f1.y); o.h[6] = f2bf(f1.z); o.h[7] = f2bf(f1.w);
    *(int4*)(xb + u * 8) = o.v;
  }
}

// ---------------- prepass: packed int4 -> bf16 W [N, K] ----------------
__global__ void dequant_w_kernel(const int* __restrict__ q,
                                 const float* __restrict__ s,
                                 unsigned short* __restrict__ W) {
  const size_t total = (size_t)N_DIM * KB2 / 4;  // 4 int32 per thread-chunk
  for (size_t u = (size_t)blockIdx.x * blockDim.x + threadIdx.x; u < total;
       u += (size_t)gridDim.x * blockDim.x) {
    size_t qi = u * 4;
    unsigned o = (unsigned)(qi >> 11);   // / 2048
    unsigned c = (unsigned)(qi & 2047);  // int32 col; 8 weights stay in one group
    float sc = s[o * NGRP + (c >> 6)];
    int4 qv = *(const int4*)(q + qi);
    union { unsigned short h[8]; int4 v; } w;
    int b;
    b = qv.x; w.h[0] = f2bf((float)((b & 15) - 8) * sc); w.h[1] = f2bf((float)(((b >> 4) & 15) - 8) * sc);
    b = qv.y; w.h[2] = f2bf((float)((b & 15) - 8) * sc); w.h[3] = f2bf((float)(((b >> 4) & 15) - 8) * sc);
    b = qv.z; w.h[4] = f2bf((float)((b & 15) - 8) * sc); w.h[5] = f2bf((float)(((b >> 4) & 15) - 8) * sc);
    b = qv.w; w.h[6] = f2bf((float)((b & 15) - 8) * sc); w.h[7] = f2bf((float)(((b >> 4) & 15) - 8) * sc);
    *(int4*)(W + qi * 2) = w.v;
  }
}

// ---------------- main GEMM: C = A[M,K] * B[N,K]^T + bias (bf16 in, f32 out) ----------------
// m97 structure: 128x128 tile, BK=64, 4 waves (2x2), 4x4 frags of 16x16x32, single-buffer LDS,
// global_load_lds width=16, 2 barriers per K-step.
__global__ __launch_bounds__(256, 2) void gemm_bf16_kernel(
    const unsigned short* __restrict__ A, const unsigned short* __restrict__ B,
    const float* __restrict__ bias, float* __restrict__ C) {
  __shared__ unsigned short As[BM * BK];  // 16 KB, linear (global_load_lds requires it)
  __shared__ unsigned short Bs[BN * BK];  // 16 KB

  const int tid = threadIdx.x;
  const int wave = tid >> 6, lane = tid & 63;
  const int m0 = blockIdx.y * BM, n0 = blockIdx.x * BN;
  const int wm = (wave >> 1) * 64, wn = (wave & 1) * 64;

  f32x4 acc[4][4] = {};

  // staging: wave w owns rows [w*32, w*32+32) of each tile; 4 instrs of 8 rows (1KB) each
  const unsigned short* Ag = A + (size_t)(m0 + wave * 32 + (lane >> 3)) * K_DIM + (lane & 7) * 8;
  const unsigned short* Bg = B + (size_t)(n0 + wave * 32 + (lane >> 3)) * K_DIM + (lane & 7) * 8;
  unsigned short* Asw = As + (wave * 32) * BK;
  unsigned short* Bsw = Bs + (wave * 32) * BK;

  const int lane16 = lane & 15;
  const int kq = (lane >> 4) * 8;

  for (int t = 0; t < K_DIM / BK; ++t) {
#pragma unroll
    for (int j = 0; j < 4; ++j) {
      gload_lds16(Ag + (size_t)j * 8 * K_DIM + t * BK, Asw + j * 8 * BK);
      gload_lds16(Bg + (size_t)j * 8 * K_DIM + t * BK, Bsw + j * 8 * BK);
    }
    __syncthreads();  // drains vmcnt; tile visible
#pragma unroll
    for (int kk = 0; kk < 2; ++kk) {
      const int ko = kk * 32 + kq;
      bf16x8 av[4], bv[4];
#pragma unroll
      for (int i = 0; i < 4; ++i)
        av[i] = *(const bf16x8*)&As[(wm + i * 16 + lane16) * BK + ko];
#pragma unroll
      for (int i = 0; i < 4; ++i)
        bv[i] = *(const bf16x8*)&Bs[(wn + i * 16 + lane16) * BK + ko];
#pragma unroll
      for (int i = 0; i < 4; ++i)
#pragma unroll
        for (int j = 0; j < 4; ++j)
          acc[i][j] = __builtin_amdgcn_mfma_f32_16x16x32_bf16(av[i], bv[j], acc[i][j], 0, 0, 0);
    }
    __syncthreads();  // before next overwrite
  }

  // epilogue: D mapping col=lane&15, row=(lane>>4)*4+r  [m89-verified]
  const int col0 = n0 + wn + lane16;
  const int row0 = m0 + wm + (lane >> 4) * 4;
#pragma unroll
  for (int j = 0; j < 4; ++j) {
    float bvs = bias[col0 + j * 16];
#pragma unroll
    for (int i = 0; i < 4; ++i) {
#pragma unroll
      for (int r = 0; r < 4; ++r) {
        C[(size_t)(row0 + i * 16 + r) * N_DIM + (col0 + j * 16)] = acc[i][j][r] + bvs;
      }
    }
  }
}

// ---------------- fallback: fused dequant GEMM (no workspace needed) ----------------
__global__ __launch_bounds__(256, 2) void gemm_fused_kernel(
    const float* __restrict__ x, const int* __restrict__ q,
    const float* __restrict__ s, const float* __restrict__ bias,
    float* __restrict__ C) {
  __shared__ unsigned short As[BM * BK];
  __shared__ unsigned short Bs[BN * BK];

  const int tid = threadIdx.x;
  const int wave = tid >> 6, lane = tid & 63;
  const int m0 = blockIdx.y * BM, n0 = blockIdx.x * BN;
  const int wm = (wave >> 1) * 64, wn = (wave & 1) * 64;

  f32x4 acc[4][4] = {};

  // staging decomposition: 2 threads per row; each covers a 32-wide k-slab
  const int r2 = tid >> 1;
  const int kh = (tid & 1) * 32;
  const float* xg = x + (size_t)(m0 + r2) * K_DIM + kh;
  const int* qg = q + (size_t)(n0 + r2) * KB2 + (tid & 1) * 16;
  const float* sg = s + (size_t)(n0 + r2) * NGRP;
  unsigned short* Asp = &As[r2 * BK + kh];
  unsigned short* Bsp = &Bs[r2 * BK + kh];

  const int lane16 = lane & 63 & 15;
  const int kq = (lane >> 4) * 8;

  for (int t = 0; t < K_DIM / BK; ++t) {
    // load + convert into regs (no LDS yet -> overlaps with prior compute)
    union { unsigned short h[8]; bf16x8 v; } oA[4], oB[4];
#pragma unroll
    for (int j = 0; j < 4; ++j) {
      float4 f0 = *(const float4*)(xg + t * BK + j * 8);
      float4 f1 = *(const float4*)(xg + t * BK + j * 8 + 4);
      oA[j].h[0] = f2bf(f0.x); oA[j].h[1] = f2bf(f0.y); oA[j].h[2] = f2bf(f0.z); oA[j].h[3] = f2bf(f0.w);
      oA[j].h[4] = f2bf(f1.x); oA[j].h[5] = f2bf(f1.y); oA[j].h[6] = f2bf(f1.z); oA[j].h[7] = f2bf(f1.w);
    }
    float sc = sg[t >> 1];  // group = (t*64 + kh)/128 = t/2 for all kh
#pragma unroll
    for (int j = 0; j < 4; ++j) {
      int4 qv = *(const int4*)(qg + t * 32 + j * 4);
      int b;
      b = qv.x; oB[j].h[0] = f2bf((float)((b & 15) - 8) * sc); oB[j].h[1] = f2bf((float)(((b >> 4) & 15) - 8) * sc);
      b = qv.y; oB[j].h[2] = f2bf((float)((b & 15) - 8) * sc); oB[j].h[3] = f2bf((float)(((b >> 4) & 15) - 8) * sc);
      b = qv.z; oB[j].h[4] = f2bf((float)((b & 15) - 8) * sc); oB[j].h[5] = f2bf((float)(((b >> 4) & 15) - 8) * sc);
      b = qv.w; oB[j].h[6] = f2bf((float)((b & 15) - 8) * sc); oB[j].h[7] = f2bf((float)(((b >> 4) & 15) - 8) * sc);
    }
    __syncthreads();  // previous compute done, safe to overwrite LDS
#pragma unroll
    for (int j = 0; j < 4; ++j) {
      *(bf16x8*)(Asp + j * 8) = oA[j].v;
      *(bf16x8*)(Bsp + j * 8) = oB[j].v;
    }
    __syncthreads();  // tile visible
#pragma unroll
    for (int kk = 0; kk < 2; ++kk) {
      const int ko = kk * 32 + kq;
      bf16x8 av[4], bv[4];
#pragma unroll
      for (int i = 0; i < 4; ++i)
        av[i] = *(const bf16x8*)&As[(wm + i * 16 + lane16) * BK + ko];
#pragma unroll
      for (int i = 0; i < 4; ++i)
        bv[i] = *(const bf16x8*)&Bs[(wn + i * 16 + lane16) * BK + ko];
#pragma unroll
      for (int i = 0; i < 4; ++i)
#pragma unroll
        for (int j = 0; j < 4; ++j)
          acc[i][j] = __builtin_amdgcn_mfma_f32_16x16x32_bf16(av[i], bv[j], acc[i][j], 0, 0, 0);
    }
  }

  const int col0 = n0 + wn + lane16;
  const int row0 = m0 + wm + (lane >> 4) * 4;
#pragma unroll
  for (int j = 0; j < 4; ++j) {
    float bvs = bias[col0 + j * 16];
#pragma unroll
    for (int i = 0; i < 4; ++i) {
#pragma unroll
      for (int r = 0; r < 4; ++r) {
        C[(size_t)(row0 + i * 16 + r) * N_DIM + (col0 + j * 16)] = acc[i][j][r] + bvs;
      }
    }
  }
}

extern "C" void kernel_launch(void* const* d_in, const int* in_sizes, int n_in,
                              void* d_out, int out_size, void* d_ws, size_t ws_size,
                              hipStream_t stream) {
  const float* x = (const float*)d_in[0];
  const int* q = (const int*)d_in[1];
  const float* s = (const float*)d_in[2];
  const float* b = (const float*)d_in[3];
  float* out = (float*)d_out;

  const size_t wb_elems = (size_t)N_DIM * K_DIM;
  const size_t ab_elems = (size_t)M_DIM * K_DIM;
  const size_t need = (wb_elems + ab_elems) * sizeof(unsigned short);  // ~107 MB

  if (ws_size >= need) {
    unsigned short* Wb = (unsigned short*)d_ws;
    unsigned short* Ab = Wb + wb_elems;
    convert_x_kernel<<<dim3(2048), dim3(256), 0, stream>>>(x, Ab);
    dequant_w_kernel<<<dim3(4096), dim3(256), 0, stream>>>(q, s, Wb);
    gemm_bf16_kernel<<<dim3(N_DIM / BN, M_DIM / BM), dim3(256), 0, stream>>>(Ab, Wb, b, out);
  } else {
    gemm_fused_kernel<<<dim3(N_DIM / BN, M_DIM / BM), dim3(256), 0, stream>>>(x, q, s, b, out);
  }
}

// Round 2
// 238.427 us; speedup vs baseline: 1.2379x; 1.2379x over previous
//
#include <hip/hip_runtime.h>
#include <stdint.h>

// QuantizedLinear: out = x @ dequant(q,s)^T + bias
#define M_DIM 2048
#define K_DIM 4096
#define N_DIM 11008
#define KB2   (K_DIM / 2)
#define NGRP  (K_DIM / 128)

// main GEMM tile
#define TBM 128
#define TBN 256
#define TBK 64
#define NT  (K_DIM / TBK)     // 64 K-steps
#define BUF_U 24576           // ushorts per LDS buffer: A 128x64 (8192) + B 256x64 (16384)

// fallback tile
#define BM 128
#define BN 128
#define BK 64

typedef __attribute__((ext_vector_type(8))) short bf16x8;
typedef __attribute__((ext_vector_type(4))) float f32x4;

__device__ __forceinline__ unsigned short f2bf(float f) {
  union { float f; unsigned u; } v; v.f = f;
  return (unsigned short)((v.u + 0x7FFFu + ((v.u >> 16) & 1u)) >> 16);
}

__device__ __forceinline__ void gload_lds16(const void* g, void* l) {
  __builtin_amdgcn_global_load_lds(
      (__attribute__((address_space(1))) void*)(g),
      (__attribute__((address_space(3))) void*)(l), 16, 0, 0);
}

// ---------------- prepass: x f32 -> bf16 ----------------
__global__ void convert_x_kernel(const float* __restrict__ x,
                                 unsigned short* __restrict__ xb) {
  const size_t total = (size_t)M_DIM * K_DIM / 8;
  for (size_t u = (size_t)blockIdx.x * blockDim.x + threadIdx.x; u < total;
       u += (size_t)gridDim.x * blockDim.x) {
    const float4* src = (const float4*)(x + u * 8);
    float4 f0 = src[0];
    float4 f1 = src[1];
    union { unsigned short h[8]; int4 v; } o;
    o.h[0] = f2bf(f0.x); o.h[1] = f2bf(f0.y); o.h[2] = f2bf(f0.z); o.h[3] = f2bf(f0.w);
    o.h[4] = f2bf(f1.x); o.h[5] = f2bf(f1.y); o.h[6] = f2bf(f1.z); o.h[7] = f2bf(f1.w);
    *(int4*)(xb + u * 8) = o.v;
  }
}

// ---------------- prepass: packed int4 -> bf16 W [N, K] ----------------
__global__ void dequant_w_kernel(const int* __restrict__ q,
                                 const float* __restrict__ s,
                                 unsigned short* __restrict__ W) {
  const size_t total = (size_t)N_DIM * KB2 / 4;
  for (size_t u = (size_t)blockIdx.x * blockDim.x + threadIdx.x; u < total;
       u += (size_t)gridDim.x * blockDim.x) {
    size_t qi = u * 4;
    unsigned o = (unsigned)(qi >> 11);
    unsigned c = (unsigned)(qi & 2047);
    float sc = s[o * NGRP + (c >> 6)];
    int4 qv = *(const int4*)(q + qi);
    union { unsigned short h[8]; int4 v; } w;
    int b;
    b = qv.x; w.h[0] = f2bf((float)((b & 15) - 8) * sc); w.h[1] = f2bf((float)(((b >> 4) & 15) - 8) * sc);
    b = qv.y; w.h[2] = f2bf((float)((b & 15) - 8) * sc); w.h[3] = f2bf((float)(((b >> 4) & 15) - 8) * sc);
    b = qv.z; w.h[4] = f2bf((float)((b & 15) - 8) * sc); w.h[5] = f2bf((float)(((b >> 4) & 15) - 8) * sc);
    b = qv.w; w.h[6] = f2bf((float)((b & 15) - 8) * sc); w.h[7] = f2bf((float)(((b >> 4) & 15) - 8) * sc);
    *(int4*)(W + qi * 2) = w.v;
  }
}

// ---------------- main GEMM: C = A[M,K] * B[N,K]^T + bias ----------------
// 128x256 tile, BK=64, 8 waves (2M x 4N), per-wave 64x64 = acc[4][4].
// 3-buffer LDS pipeline: iter t computes buf(t%3), stages tile t+2 into
// buf((t+2)%3) -> staged buffer never aliases the one being read.
// Counted s_waitcnt vmcnt(6) per K-step (tile t+2's 6 loads stay in flight).
// T2 swizzle: linear global_load_lds dest + inverse-swizzled global source
// (kx), swizzled ds_read (slot ^ (row&7)) -> 2-way conflicts only.
__global__ __launch_bounds__(512, 2) void gemm_pipe_kernel(
    const unsigned short* __restrict__ A, const unsigned short* __restrict__ B,
    const float* __restrict__ bias, float* __restrict__ C) {
  __shared__ unsigned short lds[3 * BUF_U];  // 144 KB

  const int tid = threadIdx.x;
  const int w = tid >> 6, lane = tid & 63;

  // T1: XCD-chunked bijective swizzle (688 = 8 * 86). Within an XCD, blocks
  // walk n-major -> consecutive blocks share the 2MB B-panel in that L2.
  const int hw = blockIdx.x;
  const int wg = (hw & 7) * 86 + (hw >> 3);
  const int m0 = (wg % 16) * TBM;
  const int n0 = (wg / 16) * TBN;

  // staging constants: thread covers LDS row srow (per 64-row issue), slot tid&7.
  // Inverse swizzle on the global k-offset (row&7 == srow&7 for every issue).
  const int srow = tid >> 3;
  const int kx = (((tid & 7) ^ ((tid >> 3) & 7)) << 3);
  const unsigned short* Ag = A + (size_t)(m0 + srow) * K_DIM + kx;
  const unsigned short* Bg = B + (size_t)(n0 + srow) * K_DIM + kx;
  const int aBase = w * 512;          // wave-uniform LDS staging base (ushorts)
  const int bBase = 8192 + w * 512;

#define STAGE(bufo, t2) {                                                   \
    const unsigned short* a_ = Ag + (size_t)(t2) * TBK;                     \
    const unsigned short* b_ = Bg + (size_t)(t2) * TBK;                     \
    gload_lds16(a_,                          lds + (bufo) + aBase);         \
    gload_lds16(a_ + (size_t)64 * K_DIM,     lds + (bufo) + aBase + 4096);  \
    gload_lds16(b_,                          lds + (bufo) + bBase);         \
    gload_lds16(b_ + (size_t)64 * K_DIM,     lds + (bufo) + bBase + 4096);  \
    gload_lds16(b_ + (size_t)128 * K_DIM,    lds + (bufo) + bBase + 8192);  \
    gload_lds16(b_ + (size_t)192 * K_DIM,    lds + (bufo) + bBase + 12288); \
  }

  // ds_read addressing (swizzled): addr = row*64 + ((ks*4+lq)^(row&7))*8
  const int lane16 = lane & 15, lq = lane >> 4, rx7 = lane16 & 7;
  int aRow[4], bRow[4], kOfs[2];
#pragma unroll
  for (int i = 0; i < 4; ++i) aRow[i] = ((w >> 2) * 64 + i * 16 + lane16) * 64;
#pragma unroll
  for (int j = 0; j < 4; ++j) bRow[j] = 8192 + ((w & 3) * 64 + j * 16 + lane16) * 64;
#pragma unroll
  for (int ks = 0; ks < 2; ++ks) kOfs[ks] = (((ks << 2) | lq) ^ rx7) << 3;

  f32x4 acc[4][4] = {};

  // prologue: stage tiles 0,1; wait tile 0 (6 of 12 retired)
  STAGE(0, 0);
  STAGE(BUF_U, 1);
  asm volatile("s_waitcnt vmcnt(6)" ::: "memory");
  __builtin_amdgcn_s_barrier();
  asm volatile("" ::: "memory");

  int cur = 0, stg = 2 * BUF_U;
  for (int t = 0; t < NT; ++t) {
    if (t + 2 < NT) STAGE(stg, t + 2);

    const unsigned short* Lb = lds + cur;
    bf16x8 av[2][4], bv[2][4];
#pragma unroll
    for (int ks = 0; ks < 2; ++ks)
#pragma unroll
      for (int i = 0; i < 4; ++i)
        av[ks][i] = *(const bf16x8*)&Lb[aRow[i] + kOfs[ks]];
#pragma unroll
    for (int ks = 0; ks < 2; ++ks)
#pragma unroll
      for (int j = 0; j < 4; ++j)
        bv[ks][j] = *(const bf16x8*)&Lb[bRow[j] + kOfs[ks]];

    __builtin_amdgcn_s_setprio(1);
#pragma unroll
    for (int ks = 0; ks < 2; ++ks)
#pragma unroll
      for (int i = 0; i < 4; ++i)
#pragma unroll
        for (int j = 0; j < 4; ++j)
          acc[i][j] = __builtin_amdgcn_mfma_f32_16x16x32_bf16(av[ks][i], bv[ks][j], acc[i][j], 0, 0, 0);
    __builtin_amdgcn_s_setprio(0);

    if (t == NT - 1) break;
    if (t == NT - 2) {
      asm volatile("s_waitcnt vmcnt(0)" ::: "memory");  // final tile must land
    } else {
      asm volatile("s_waitcnt vmcnt(6)" ::: "memory");  // keep tile t+2 in flight
    }
    __builtin_amdgcn_s_barrier();
    asm volatile("" ::: "memory");
    cur = (cur == 2 * BUF_U) ? 0 : cur + BUF_U;
    stg = (stg == 2 * BUF_U) ? 0 : stg + BUF_U;
  }
#undef STAGE

  // epilogue: D mapping col=lane&15, row=(lane>>4)*4+r
  const int row0 = m0 + (w >> 2) * 64 + (lane >> 4) * 4;
  const int col0 = n0 + (w & 3) * 64 + lane16;
#pragma unroll
  for (int j = 0; j < 4; ++j) {
    float bvs = bias[col0 + j * 16];
#pragma unroll
    for (int i = 0; i < 4; ++i) {
#pragma unroll
      for (int r = 0; r < 4; ++r) {
        C[(size_t)(row0 + i * 16 + r) * N_DIM + (col0 + j * 16)] = acc[i][j][r] + bvs;
      }
    }
  }
}

// ---------------- fallback: fused dequant GEMM (no workspace needed) ----------------
__global__ __launch_bounds__(256, 2) void gemm_fused_kernel(
    const float* __restrict__ x, const int* __restrict__ q,
    const float* __restrict__ s, const float* __restrict__ bias,
    float* __restrict__ C) {
  __shared__ unsigned short As[BM * BK];
  __shared__ unsigned short Bs[BN * BK];

  const int tid = threadIdx.x;
  const int wave = tid >> 6, lane = tid & 63;
  const int m0 = blockIdx.y * BM, n0 = blockIdx.x * BN;
  const int wm = (wave >> 1) * 64, wn = (wave & 1) * 64;

  f32x4 acc[4][4] = {};

  const int r2 = tid >> 1;
  const int kh = (tid & 1) * 32;
  const float* xg = x + (size_t)(m0 + r2) * K_DIM + kh;
  const int* qg = q + (size_t)(n0 + r2) * KB2 + (tid & 1) * 16;
  const float* sg = s + (size_t)(n0 + r2) * NGRP;
  unsigned short* Asp = &As[r2 * BK + kh];
  unsigned short* Bsp = &Bs[r2 * BK + kh];

  const int lane16 = lane & 15;
  const int kq = (lane >> 4) * 8;

  for (int t = 0; t < K_DIM / BK; ++t) {
    union { unsigned short h[8]; bf16x8 v; } oA[4], oB[4];
#pragma unroll
    for (int j = 0; j < 4; ++j) {
      float4 f0 = *(const float4*)(xg + t * BK + j * 8);
      float4 f1 = *(const float4*)(xg + t * BK + j * 8 + 4);
      oA[j].h[0] = f2bf(f0.x); oA[j].h[1] = f2bf(f0.y); oA[j].h[2] = f2bf(f0.z); oA[j].h[3] = f2bf(f0.w);
      oA[j].h[4] = f2bf(f1.x); oA[j].h[5] = f2bf(f1.y); oA[j].h[6] = f2bf(f1.z); oA[j].h[7] = f2bf(f1.w);
    }
    float sc = sg[t >> 1];
#pragma unroll
    for (int j = 0; j < 4; ++j) {
      int4 qv = *(const int4*)(qg + t * 32 + j * 4);
      int b;
      b = qv.x; oB[j].h[0] = f2bf((float)((b & 15) - 8) * sc); oB[j].h[1] = f2bf((float)(((b >> 4) & 15) - 8) * sc);
      b = qv.y; oB[j].h[2] = f2bf((float)((b & 15) - 8) * sc); oB[j].h[3] = f2bf((float)(((b >> 4) & 15) - 8) * sc);
      b = qv.z; oB[j].h[4] = f2bf((float)((b & 15) - 8) * sc); oB[j].h[5] = f2bf((float)(((b >> 4) & 15) - 8) * sc);
      b = qv.w; oB[j].h[6] = f2bf((float)((b & 15) - 8) * sc); oB[j].h[7] = f2bf((float)(((b >> 4) & 15) - 8) * sc);
    }
    __syncthreads();
#pragma unroll
    for (int j = 0; j < 4; ++j) {
      *(bf16x8*)(Asp + j * 8) = oA[j].v;
      *(bf16x8*)(Bsp + j * 8) = oB[j].v;
    }
    __syncthreads();
#pragma unroll
    for (int kk = 0; kk < 2; ++kk) {
      const int ko = kk * 32 + kq;
      bf16x8 av[4], bv[4];
#pragma unroll
      for (int i = 0; i < 4; ++i)
        av[i] = *(const bf16x8*)&As[(wm + i * 16 + lane16) * BK + ko];
#pragma unroll
      for (int i = 0; i < 4; ++i)
        bv[i] = *(const bf16x8*)&Bs[(wn + i * 16 + lane16) * BK + ko];
#pragma unroll
      for (int i = 0; i < 4; ++i)
#pragma unroll
        for (int j = 0; j < 4; ++j)
          acc[i][j] = __builtin_amdgcn_mfma_f32_16x16x32_bf16(av[i], bv[j], acc[i][j], 0, 0, 0);
    }
  }

  const int col0 = n0 + wn + lane16;
  const int row0 = m0 + wm + (lane >> 4) * 4;
#pragma unroll
  for (int j = 0; j < 4; ++j) {
    float bvs = bias[col0 + j * 16];
#pragma unroll
    for (int i = 0; i < 4; ++i) {
#pragma unroll
      for (int r = 0; r < 4; ++r) {
        C[(size_t)(row0 + i * 16 + r) * N_DIM + (col0 + j * 16)] = acc[i][j][r] + bvs;
      }
    }
  }
}

extern "C" void kernel_launch(void* const* d_in, const int* in_sizes, int n_in,
                              void* d_out, int out_size, void* d_ws, size_t ws_size,
                              hipStream_t stream) {
  const float* x = (const float*)d_in[0];
  const int* q = (const int*)d_in[1];
  const float* s = (const float*)d_in[2];
  const float* b = (const float*)d_in[3];
  float* out = (float*)d_out;

  const size_t wb_elems = (size_t)N_DIM * K_DIM;
  const size_t ab_elems = (size_t)M_DIM * K_DIM;
  const size_t need = (wb_elems + ab_elems) * sizeof(unsigned short);

  if (ws_size >= need) {
    unsigned short* Wb = (unsigned short*)d_ws;
    unsigned short* Ab = Wb + wb_elems;
    convert_x_kernel<<<dim3(2048), dim3(256), 0, stream>>>(x, Ab);
    dequant_w_kernel<<<dim3(4096), dim3(256), 0, stream>>>(q, s, Wb);
    gemm_pipe_kernel<<<dim3((N_DIM / TBN) * (M_DIM / TBM)), dim3(512), 0, stream>>>(Ab, Wb, b, out);
  } else {
    gemm_fused_kernel<<<dim3(N_DIM / BN, M_DIM / BM), dim3(256), 0, stream>>>(x, q, s, b, out);
  }
}